// Round 4
// baseline (246.462 us; speedup 1.0000x reference)
//
#include <hip/hip_runtime.h>

typedef short bf16x8 __attribute__((ext_vector_type(8)));
typedef float f32x4 __attribute__((ext_vector_type(4)));

#define T_LEN 4096
#define NB    4
#define HID   1024
#define HD    64

// fp32 -> bf16 bits, round-to-nearest-even
__device__ __forceinline__ unsigned short f2bf(float f) {
    union { float f; unsigned int u; } v; v.f = f;
    unsigned int u = v.u;
    u += 0x7fffu + ((u >> 16) & 1u);
    return (unsigned short)(u >> 16);
}

// ---------------- W transpose: [1024][64] x3 fp32 -> Wt[192][1024] bf16 ----------------
__global__ __launch_bounds__(256) void wtrans_kernel(
    const float* __restrict__ wq, const float* __restrict__ wk,
    const float* __restrict__ wv, unsigned short* __restrict__ Wt)
{
    const int idx = blockIdx.x * 256 + threadIdx.x;   // 192*1024 total
    const int k = idx & 1023;
    const int n = idx >> 10;                          // 0..191
    const float* w = (n < 64) ? wq : ((n < 128) ? wk : wv);
    Wt[(size_t)n * 1024 + k] = f2bf(w[(size_t)k * 64 + (n & 63)]);
}

// ---------------- QKV projection GEMM: M=16384, N=192, K=1024 (bf16 MFMA) -------------
// Writes Q,K row-major [B*T][64] bf16 and V transposed VT[B][64][T] bf16.
__global__ __launch_bounds__(256) void qkv_proj_kernel(
    const float* __restrict__ x, const unsigned short* __restrict__ Wt,
    unsigned short* __restrict__ Qb, unsigned short* __restrict__ Kb,
    unsigned short* __restrict__ VT)
{
    __shared__ unsigned short Alds[64][40];    // 64 rows x 32 k, +8 pad (2-way banks)
    __shared__ unsigned short Wlds[192][40];   // 192 n   x 32 k, +8 pad
    const int tid  = threadIdx.x;
    const int wave = tid >> 6, lane = tid & 63;
    const int g = lane >> 4, lr = lane & 15;
    const int m0 = blockIdx.x * 64;

    f32x4 acc[12];
#pragma unroll
    for (int i = 0; i < 12; ++i) acc[i] = (f32x4)(0.0f);

    for (int k0 = 0; k0 < HID; k0 += 32) {
        __syncthreads();
        { // stage x tile 64x32 fp32 -> bf16 (coalesced float4 loads)
            const int r = tid >> 3;
            const int c = (tid & 7) * 4;
#pragma unroll
            for (int h = 0; h < 2; ++h) {
                const int row = r + h * 32;
                const float4 v = *(const float4*)(x + (size_t)(m0 + row) * HID + k0 + c);
                ushort4 pk = make_ushort4(f2bf(v.x), f2bf(v.y), f2bf(v.z), f2bf(v.w));
                *(ushort4*)&Alds[row][c] = pk;
            }
        }
        { // stage Wt tile 192x32 bf16 (16B chunk copies)
#pragma unroll
            for (int j3 = 0; j3 < 3; ++j3) {
                const int j = tid * 3 + j3;          // 0..767
                const int n = j >> 2, part = (j & 3) * 8;
                const uint4 v = *(const uint4*)(Wt + (size_t)n * 1024 + k0 + part);
                *(uint4*)&Wlds[n][part] = v;
            }
        }
        __syncthreads();
        const bf16x8 af = *(const bf16x8*)&Alds[wave * 16 + lr][g * 8];
#pragma unroll
        for (int nt = 0; nt < 12; ++nt) {
            const bf16x8 bfr = *(const bf16x8*)&Wlds[nt * 16 + lr][g * 8];
            acc[nt] = __builtin_amdgcn_mfma_f32_16x16x32_bf16(af, bfr, acc[nt], 0, 0, 0);
        }
    }

    // epilogue: rows m0 + wave*16 + 4g + r ; cols nt*16 + lr
    const int rowbase = m0 + wave * 16 + g * 4;
#pragma unroll
    for (int nt = 0; nt < 4; ++nt)
#pragma unroll
        for (int r = 0; r < 4; ++r)
            Qb[(size_t)(rowbase + r) * HD + nt * 16 + lr] = f2bf(acc[nt][r]);
#pragma unroll
    for (int nt = 0; nt < 4; ++nt)
#pragma unroll
        for (int r = 0; r < 4; ++r)
            Kb[(size_t)(rowbase + r) * HD + nt * 16 + lr] = f2bf(acc[nt + 4][r]);
    const int bb = m0 >> 12;                 // batch (64-row tiles never straddle batches)
    const int t0 = (m0 & 4095) + wave * 16 + g * 4;
#pragma unroll
    for (int nt = 0; nt < 4; ++nt) {
        const int dcol = nt * 16 + lr;
        ushort4 pk;
        pk.x = f2bf(acc[nt + 8][0]); pk.y = f2bf(acc[nt + 8][1]);
        pk.z = f2bf(acc[nt + 8][2]); pk.w = f2bf(acc[nt + 8][3]);
        *(ushort4*)(VT + (size_t)(bb * 64 + dcol) * T_LEN + t0) = pk;
    }
}

// ---------------- Flash attention (causal, D=64), bf16 MFMA ----------------
template <bool MASKED>
__device__ __forceinline__ void kv_tile(
    const int kv0, const int qw0, const int g, const int lr,
    const unsigned short* __restrict__ kb, const unsigned short* __restrict__ vb,
    unsigned short (*Plds)[72],
    const bf16x8 qf0, const bf16x8 qf1,
    f32x4 oacc[4], float mrow[4], float lrow[4])
{
    const float SCL = 0.18033688011112042f;  // (1/8) * log2(e)
    // S = Q K^T  (per-lane: rows 4g+r, col nt*16+lr)
    f32x4 s[4];
#pragma unroll
    for (int nt = 0; nt < 4; ++nt) {
        const unsigned short* kp = kb + (size_t)(kv0 + nt * 16 + lr) * HD + g * 8;
        const bf16x8 kf0 = *(const bf16x8*)kp;
        const bf16x8 kf1 = *(const bf16x8*)(kp + 32);
        f32x4 a = (f32x4)(0.0f);
        a = __builtin_amdgcn_mfma_f32_16x16x32_bf16(qf0, kf0, a, 0, 0, 0);
        a = __builtin_amdgcn_mfma_f32_16x16x32_bf16(qf1, kf1, a, 0, 0, 0);
        s[nt] = a;
    }
    if (MASKED) {
#pragma unroll
        for (int nt = 0; nt < 4; ++nt) {
            const int kj = kv0 + nt * 16 + lr;
#pragma unroll
            for (int r = 0; r < 4; ++r)
                if (kj > qw0 + g * 4 + r) s[nt][r] = -3.0e38f;
        }
    }
    // row max over 64 cols: 4 local + 16-lane butterfly
    float tm[4];
#pragma unroll
    for (int r = 0; r < 4; ++r)
        tm[r] = fmaxf(fmaxf(s[0][r], s[1][r]), fmaxf(s[2][r], s[3][r]));
#pragma unroll
    for (int m = 1; m < 16; m <<= 1)
#pragma unroll
        for (int r = 0; r < 4; ++r)
            tm[r] = fmaxf(tm[r], __shfl_xor(tm[r], m, 64));

    float al[4];
#pragma unroll
    for (int r = 0; r < 4; ++r) {
        const float mn = fmaxf(mrow[r], tm[r]);
        al[r] = __builtin_amdgcn_exp2f((mrow[r] - mn) * SCL);
        mrow[r] = mn;
    }
    float ps[4] = {0.f, 0.f, 0.f, 0.f};
#pragma unroll
    for (int nt = 0; nt < 4; ++nt)
#pragma unroll
        for (int r = 0; r < 4; ++r) {
            const float p = __builtin_amdgcn_exp2f((s[nt][r] - mrow[r]) * SCL);
            ps[r] += p;   // per-lane partial; reduced across 16 lanes at the end
            Plds[g * 4 + r][nt * 16 + lr] = f2bf(p);
        }
#pragma unroll
    for (int r = 0; r < 4; ++r) lrow[r] = lrow[r] * al[r] + ps[r];
#pragma unroll
    for (int dt = 0; dt < 4; ++dt)
#pragma unroll
        for (int r = 0; r < 4; ++r) oacc[dt][r] *= al[r];

    // P (from LDS, A-frag layout) x V (from VT, contiguous B-frags)
    const bf16x8 pf0 = *(const bf16x8*)&Plds[lr][g * 8];
    const bf16x8 pf1 = *(const bf16x8*)&Plds[lr][32 + g * 8];
#pragma unroll
    for (int dt = 0; dt < 4; ++dt) {
        const unsigned short* vp = vb + (size_t)(dt * 16 + lr) * T_LEN + kv0 + g * 8;
        const bf16x8 vf0 = *(const bf16x8*)vp;
        const bf16x8 vf1 = *(const bf16x8*)(vp + 32);
        oacc[dt] = __builtin_amdgcn_mfma_f32_16x16x32_bf16(pf0, vf0, oacc[dt], 0, 0, 0);
        oacc[dt] = __builtin_amdgcn_mfma_f32_16x16x32_bf16(pf1, vf1, oacc[dt], 0, 0, 0);
    }
}

__global__ __launch_bounds__(256) void attn_kernel(
    const unsigned short* __restrict__ Qb, const unsigned short* __restrict__ Kb,
    const unsigned short* __restrict__ VT, float* __restrict__ out)
{
    __shared__ unsigned short Plds[4][16][72];   // per-wave P tile, padded
    const int tid = threadIdx.x;
    const int wave = tid >> 6, lane = tid & 63;
    const int g = lane >> 4, lr = lane & 15;
    const int b  = blockIdx.x >> 6;              // 64 q-blocks per batch
    const int q0 = (blockIdx.x & 63) * 64;
    const int qw0 = q0 + wave * 16;              // this wave's 16 q-rows

    const unsigned short* qp = Qb + (size_t)(b * T_LEN + qw0 + lr) * HD + g * 8;
    const bf16x8 qf0 = *(const bf16x8*)qp;
    const bf16x8 qf1 = *(const bf16x8*)(qp + 32);

    const unsigned short* kb = Kb + (size_t)b * T_LEN * HD;
    const unsigned short* vb = VT + (size_t)b * HD * T_LEN;

    f32x4 oacc[4];
#pragma unroll
    for (int i = 0; i < 4; ++i) oacc[i] = (f32x4)(0.0f);
    float mrow[4] = {-3.0e38f, -3.0e38f, -3.0e38f, -3.0e38f};
    float lrow[4] = {0.f, 0.f, 0.f, 0.f};

    const int nfull = qw0 >> 6;                  // full (unmasked) KV tiles
    for (int it = 0; it < nfull; ++it)
        kv_tile<false>(it * 64, qw0, g, lr, kb, vb, Plds[wave], qf0, qf1, oacc, mrow, lrow);
    kv_tile<true>(nfull * 64, qw0, g, lr, kb, vb, Plds[wave], qf0, qf1, oacc, mrow, lrow);

    // complete the row-sum across the 16-lane group (alpha factors were group-uniform)
#pragma unroll
    for (int m = 1; m < 16; m <<= 1)
#pragma unroll
        for (int r = 0; r < 4; ++r) lrow[r] += __shfl_xor(lrow[r], m, 64);

#pragma unroll
    for (int r = 0; r < 4; ++r) {
        const float inv = 1.0f / lrow[r];
        const size_t rowoff = (size_t)(b * T_LEN + qw0 + g * 4 + r) * HD;
#pragma unroll
        for (int dt = 0; dt < 4; ++dt)
            out[rowoff + dt * 16 + lr] = oacc[dt][r] * inv;
    }
}

extern "C" void kernel_launch(void* const* d_in, const int* in_sizes, int n_in,
                              void* d_out, int out_size, void* d_ws, size_t ws_size,
                              hipStream_t stream) {
    const float* x  = (const float*)d_in[0];
    const float* wq = (const float*)d_in[1];
    const float* wk = (const float*)d_in[2];
    const float* wv = (const float*)d_in[3];
    float* out = (float*)d_out;

    unsigned short* Qb = (unsigned short*)d_ws;                 // [16384][64] bf16
    unsigned short* Kb = Qb + (size_t)NB * T_LEN * HD;          // [16384][64]
    unsigned short* VT = Kb + (size_t)NB * T_LEN * HD;          // [4][64][4096]
    unsigned short* Wt = VT + (size_t)NB * HD * T_LEN;          // [192][1024]

    wtrans_kernel<<<768, 256, 0, stream>>>(wq, wk, wv, Wt);
    qkv_proj_kernel<<<256, 256, 0, stream>>>(x, Wt, Qb, Kb, VT);
    attn_kernel<<<NB * (T_LEN / 64), 256, 0, stream>>>(Qb, Kb, VT, out);
}

// Round 5
// 106.232 us; speedup vs baseline: 2.3200x; 2.3200x over previous
//
#include <hip/hip_runtime.h>

typedef short bf16x8 __attribute__((ext_vector_type(8)));
typedef float f32x4 __attribute__((ext_vector_type(4)));

#define T_LEN 4096
#define NB    4
#define HID   1024
#define HD    64

// fp32 -> bf16 bits, round-to-nearest-even
__device__ __forceinline__ unsigned short f2bf(float f) {
    union { float f; unsigned int u; } v; v.f = f;
    unsigned int u = v.u;
    u += 0x7fffu + ((u >> 16) & 1u);
    return (unsigned short)(u >> 16);
}

// ---------------- W transpose: [1024][64] x3 fp32 -> Wt[192][1024] bf16 ----------------
__global__ __launch_bounds__(256) void wtrans_kernel(
    const float* __restrict__ wq, const float* __restrict__ wk,
    const float* __restrict__ wv, unsigned short* __restrict__ Wt)
{
    const int idx = blockIdx.x * 256 + threadIdx.x;   // 192*1024 total
    const int k = idx & 1023;
    const int n = idx >> 10;                          // 0..191
    const float* w = (n < 64) ? wq : ((n < 128) ? wk : wv);
    Wt[(size_t)n * 1024 + k] = f2bf(w[(size_t)k * 64 + (n & 63)]);
}

// ---------------- QKV projection GEMM: M=16384, N=192, K=1024 (bf16 MFMA) -------------
// Writes Q row-major [B*T][64] bf16; K packed Kpk[b][t/16][d/8][t%16][8];
// V packed Vpk[b][t/8][d][t%8]  (both in exact MFMA B-fragment order for attn).
__global__ __launch_bounds__(256) void qkv_proj_kernel(
    const float* __restrict__ x, const unsigned short* __restrict__ Wt,
    unsigned short* __restrict__ Qb, unsigned short* __restrict__ Kpk,
    unsigned short* __restrict__ Vpk)
{
    __shared__ unsigned short Alds[64][40];    // 64 rows x 32 k, +8 pad
    __shared__ unsigned short Wlds[192][40];   // 192 n   x 32 k, +8 pad
    const int tid  = threadIdx.x;
    const int wave = tid >> 6, lane = tid & 63;
    const int g = lane >> 4, lr = lane & 15;
    const int m0 = blockIdx.x * 64;

    f32x4 acc[12];
#pragma unroll
    for (int i = 0; i < 12; ++i) acc[i] = (f32x4)(0.0f);

    for (int k0 = 0; k0 < HID; k0 += 32) {
        __syncthreads();
        { // stage x tile 64x32 fp32 -> bf16 (coalesced float4 loads)
            const int r = tid >> 3;
            const int c = (tid & 7) * 4;
#pragma unroll
            for (int h = 0; h < 2; ++h) {
                const int row = r + h * 32;
                const float4 v = *(const float4*)(x + (size_t)(m0 + row) * HID + k0 + c);
                ushort4 pk = make_ushort4(f2bf(v.x), f2bf(v.y), f2bf(v.z), f2bf(v.w));
                *(ushort4*)&Alds[row][c] = pk;
            }
        }
        { // stage Wt tile 192x32 bf16
#pragma unroll
            for (int j3 = 0; j3 < 3; ++j3) {
                const int j = tid * 3 + j3;          // 0..767
                const int n = j >> 2, part = (j & 3) * 8;
                const uint4 v = *(const uint4*)(Wt + (size_t)n * 1024 + k0 + part);
                *(uint4*)&Wlds[n][part] = v;
            }
        }
        __syncthreads();
        const bf16x8 af = *(const bf16x8*)&Alds[wave * 16 + lr][g * 8];
#pragma unroll
        for (int nt = 0; nt < 12; ++nt) {
            const bf16x8 bfr = *(const bf16x8*)&Wlds[nt * 16 + lr][g * 8];
            acc[nt] = __builtin_amdgcn_mfma_f32_16x16x32_bf16(af, bfr, acc[nt], 0, 0, 0);
        }
    }

    // epilogue: rows t = m0 + wave*16 + g*4 + r ; cols d = nt*16 + lr
    const int rowbase = m0 + wave * 16 + g * 4;
    const int bb = rowbase >> 12;                   // batch
    const size_t bpk = (size_t)bb * (T_LEN * HD);   // 262144 elems per batch
#pragma unroll
    for (int nt = 0; nt < 4; ++nt)
#pragma unroll
        for (int r = 0; r < 4; ++r)
            Qb[(size_t)(rowbase + r) * HD + nt * 16 + lr] = f2bf(acc[nt][r]);
#pragma unroll
    for (int nt = 0; nt < 4; ++nt)
#pragma unroll
        for (int r = 0; r < 4; ++r) {
            const int tl = (rowbase + r) & 4095;
            const int d  = nt * 16 + lr;
            Kpk[bpk + ((((tl >> 4) * 8 + (d >> 3)) * 16 + (tl & 15)) << 3) + (d & 7)]
                = f2bf(acc[nt + 4][r]);
        }
#pragma unroll
    for (int nt = 0; nt < 4; ++nt)
#pragma unroll
        for (int r = 0; r < 4; ++r) {
            const int tl = (rowbase + r) & 4095;
            const int d  = nt * 16 + lr;
            Vpk[bpk + (((tl >> 3) * 64 + d) << 3) + (tl & 7)] = f2bf(acc[nt + 8][r]);
        }
}

// ---------------- Flash attention partials (split-KV, causal, D=64) ----------------
template <bool MASKED>
__device__ __forceinline__ void kv_tile_pk(
    const int t0, const int qw0, const int lane, const int g, const int lr,
    const unsigned short* __restrict__ kpk_b, const unsigned short* __restrict__ vpk_b,
    unsigned short (*Plds)[72],
    const bf16x8 qf0, const bf16x8 qf1,
    f32x4 oacc[4], float mrow[4], float lrow[4])
{
    const float SCL = 0.18033688011112042f;  // (1/8) * log2(e)
    f32x4 s[4];
#pragma unroll
    for (int nt = 0; nt < 4; ++nt) {
        // coalesced: 64 lanes read 1KB contiguous per fragment
        const unsigned short* kp = kpk_b + (((size_t)((t0 >> 4) + nt)) << 10) + (lane << 3);
        const bf16x8 kf0 = *(const bf16x8*)kp;
        const bf16x8 kf1 = *(const bf16x8*)(kp + 512);
        f32x4 a = (f32x4)(0.0f);
        a = __builtin_amdgcn_mfma_f32_16x16x32_bf16(qf0, kf0, a, 0, 0, 0);
        a = __builtin_amdgcn_mfma_f32_16x16x32_bf16(qf1, kf1, a, 0, 0, 0);
        s[nt] = a;
    }
    if (MASKED) {
#pragma unroll
        for (int nt = 0; nt < 4; ++nt) {
            const int kj = t0 + nt * 16 + lr;
#pragma unroll
            for (int r = 0; r < 4; ++r)
                if (kj > qw0 + g * 4 + r) s[nt][r] = -3.0e38f;
        }
    }
    float tm[4];
#pragma unroll
    for (int r = 0; r < 4; ++r)
        tm[r] = fmaxf(fmaxf(s[0][r], s[1][r]), fmaxf(s[2][r], s[3][r]));
#pragma unroll
    for (int m = 1; m < 16; m <<= 1)
#pragma unroll
        for (int r = 0; r < 4; ++r)
            tm[r] = fmaxf(tm[r], __shfl_xor(tm[r], m, 64));

    float al[4];
#pragma unroll
    for (int r = 0; r < 4; ++r) {
        const float mn = fmaxf(mrow[r], tm[r]);
        al[r] = __builtin_amdgcn_exp2f((mrow[r] - mn) * SCL);
        mrow[r] = mn;
    }
    float ps[4] = {0.f, 0.f, 0.f, 0.f};
#pragma unroll
    for (int nt = 0; nt < 4; ++nt)
#pragma unroll
        for (int r = 0; r < 4; ++r) {
            const float p = __builtin_amdgcn_exp2f((s[nt][r] - mrow[r]) * SCL);
            ps[r] += p;
            Plds[g * 4 + r][nt * 16 + lr] = f2bf(p);
        }
#pragma unroll
    for (int r = 0; r < 4; ++r) lrow[r] = lrow[r] * al[r] + ps[r];
#pragma unroll
    for (int dt = 0; dt < 4; ++dt)
#pragma unroll
        for (int r = 0; r < 4; ++r) oacc[dt][r] *= al[r];

    const bf16x8 pf0 = *(const bf16x8*)&Plds[lr][g * 8];
    const bf16x8 pf1 = *(const bf16x8*)&Plds[lr][32 + g * 8];
    const unsigned short* v0b = vpk_b + (((size_t)((t0 >> 3) + g)) << 9) + (lr << 3);
    const unsigned short* v1b = vpk_b + (((size_t)((t0 >> 3) + 4 + g)) << 9) + (lr << 3);
#pragma unroll
    for (int dt = 0; dt < 4; ++dt) {
        const bf16x8 vf0 = *(const bf16x8*)(v0b + dt * 128);
        const bf16x8 vf1 = *(const bf16x8*)(v1b + dt * 128);
        oacc[dt] = __builtin_amdgcn_mfma_f32_16x16x32_bf16(pf0, vf0, oacc[dt], 0, 0, 0);
        oacc[dt] = __builtin_amdgcn_mfma_f32_16x16x32_bf16(pf1, vf1, oacc[dt], 0, 0, 0);
    }
}

// grid: ((b*64 + qi)*8 + c); chunk c covers kv [c*512, (c+1)*512)
__global__ __launch_bounds__(256) void attn_part_kernel(
    const unsigned short* __restrict__ Qb, const unsigned short* __restrict__ Kpk,
    const unsigned short* __restrict__ Vpk,
    float* __restrict__ Opart, float* __restrict__ Mpart, float* __restrict__ Lpart)
{
    const int c  = blockIdx.x & 7;
    const int qi = (blockIdx.x >> 3) & 63;
    const int b  = blockIdx.x >> 9;
    const int diagc = qi >> 3;
    if (c > diagc) return;                       // invalid (future) chunk

    __shared__ unsigned short Plds[4][16][72];
    const int tid = threadIdx.x;
    const int wave = tid >> 6, lane = tid & 63;
    const int g = lane >> 4, lr = lane & 15;
    const int qw0 = qi * 64 + wave * 16;         // wave's first q row (in batch)
    const int kvbase = c << 9;

    const unsigned short* qp = Qb + (size_t)(b * T_LEN + qw0 + lr) * HD + g * 8;
    const bf16x8 qf0 = *(const bf16x8*)qp;
    const bf16x8 qf1 = *(const bf16x8*)(qp + 32);
    const unsigned short* kpk_b = Kpk + (size_t)b * (T_LEN * HD);
    const unsigned short* vpk_b = Vpk + (size_t)b * (T_LEN * HD);

    f32x4 oacc[4];
#pragma unroll
    for (int i = 0; i < 4; ++i) oacc[i] = (f32x4)(0.0f);
    float mrow[4] = {-3.0e38f, -3.0e38f, -3.0e38f, -3.0e38f};
    float lrow[4] = {0.f, 0.f, 0.f, 0.f};

    const bool diag = (c == diagc);
    const int nfull = diag ? ((qw0 + 1 - kvbase) >> 6) : 8;
    for (int it = 0; it < nfull; ++it)
        kv_tile_pk<false>(kvbase + it * 64, qw0, lane, g, lr, kpk_b, vpk_b,
                          Plds[wave], qf0, qf1, oacc, mrow, lrow);
    if (diag)
        kv_tile_pk<true>(kvbase + nfull * 64, qw0, lane, g, lr, kpk_b, vpk_b,
                         Plds[wave], qf0, qf1, oacc, mrow, lrow);

    // finish the row-sum across the 16-lane group
#pragma unroll
    for (int m = 1; m < 16; m <<= 1)
#pragma unroll
        for (int r = 0; r < 4; ++r) lrow[r] += __shfl_xor(lrow[r], m, 64);

    // write partials (unnormalized)
    float* Op = Opart + ((size_t)blockIdx.x << 12);          // [64][64]
    float* Mp = Mpart + ((size_t)blockIdx.x << 6);
    float* Lp = Lpart + ((size_t)blockIdx.x << 6);
#pragma unroll
    for (int r = 0; r < 4; ++r) {
        const int wrow = wave * 16 + g * 4 + r;
        if (lr == 0) { Mp[wrow] = mrow[r]; Lp[wrow] = lrow[r]; }
#pragma unroll
        for (int dt = 0; dt < 4; ++dt)
            Op[wrow * 64 + dt * 16 + lr] = oacc[dt][r];
    }
}

// ---------------- merge partials: one block per (b, qi) ----------------
__global__ __launch_bounds__(256) void attn_merge_kernel(
    const float* __restrict__ Opart, const float* __restrict__ Mpart,
    const float* __restrict__ Lpart, float* __restrict__ out)
{
    const int qi = blockIdx.x & 63, b = blockIdx.x >> 6;
    const int nch = (qi >> 3) + 1;
    const int t = threadIdx.x;
    const int row = t >> 2, d0 = (t & 3) << 4;
    const size_t pb = (size_t)blockIdx.x << 3;
    const float SCL = 0.18033688011112042f;

    float mv[8], wv[8];
    float M = -3.0e38f;
#pragma unroll
    for (int c = 0; c < 8; ++c) {
        mv[c] = (c < nch) ? Mpart[((pb + c) << 6) + row] : -3.0e38f;
        M = fmaxf(M, mv[c]);
    }
    float L = 0.f;
#pragma unroll
    for (int c = 0; c < 8; ++c) {
        wv[c] = (c < nch) ? __builtin_amdgcn_exp2f((mv[c] - M) * SCL) : 0.f;
        if (c < nch) L += Lpart[((pb + c) << 6) + row] * wv[c];
    }
    const float inv = 1.0f / L;

    f32x4 o[4];
#pragma unroll
    for (int i = 0; i < 4; ++i) o[i] = (f32x4)(0.0f);
#pragma unroll
    for (int c = 0; c < 8; ++c) {
        if (c < nch) {
            const f32x4* src = (const f32x4*)(Opart + (((pb + c) << 6) + row) * 64 + d0);
#pragma unroll
            for (int i = 0; i < 4; ++i) {
                const f32x4 v = src[i];
#pragma unroll
                for (int j = 0; j < 4; ++j) o[i][j] += v[j] * wv[c];
            }
        }
    }
    f32x4* dst = (f32x4*)(out + ((size_t)(b * T_LEN + qi * 64 + row) * HD) + d0);
#pragma unroll
    for (int i = 0; i < 4; ++i) {
        f32x4 v;
#pragma unroll
        for (int j = 0; j < 4; ++j) v[j] = o[i][j] * inv;
        dst[i] = v;
    }
}

extern "C" void kernel_launch(void* const* d_in, const int* in_sizes, int n_in,
                              void* d_out, int out_size, void* d_ws, size_t ws_size,
                              hipStream_t stream) {
    const float* x  = (const float*)d_in[0];
    const float* wq = (const float*)d_in[1];
    const float* wk = (const float*)d_in[2];
    const float* wv = (const float*)d_in[3];
    float* out = (float*)d_out;

    // workspace layout (f32 arrays first for alignment)
    float* Opart = (float*)d_ws;                              // 2048*64*64 f32 = 32 MB
    float* Mpart = Opart + ((size_t)2048 * 4096);             // 2048*64 f32
    float* Lpart = Mpart + ((size_t)2048 * 64);               // 2048*64 f32
    unsigned short* Qb  = (unsigned short*)(Lpart + (size_t)2048 * 64);  // [16384][64] bf16
    unsigned short* Kpk = Qb  + (size_t)NB * T_LEN * HD;      // packed K fragments
    unsigned short* Vpk = Kpk + (size_t)NB * T_LEN * HD;      // packed V fragments
    unsigned short* Wt  = Vpk + (size_t)NB * T_LEN * HD;      // [192][1024]

    wtrans_kernel<<<768, 256, 0, stream>>>(wq, wk, wv, Wt);
    qkv_proj_kernel<<<256, 256, 0, stream>>>(x, Wt, Qb, Kpk, Vpk);
    attn_part_kernel<<<NB * 64 * 8, 256, 0, stream>>>(Qb, Kpk, Vpk, Opart, Mpart, Lpart);
    attn_merge_kernel<<<NB * 64, 256, 0, stream>>>(Opart, Mpart, Lpart, out);
}

// Round 6
// 98.912 us; speedup vs baseline: 2.4917x; 1.0740x over previous
//
#include <hip/hip_runtime.h>

typedef short bf16x8 __attribute__((ext_vector_type(8)));
typedef float f32x4 __attribute__((ext_vector_type(4)));

#define T_LEN 4096
#define NB    4
#define HID   1024
#define HD    64

// fp32 -> bf16 bits, round-to-nearest-even
__device__ __forceinline__ unsigned short f2bf(float f) {
    union { float f; unsigned int u; } v; v.f = f;
    unsigned int u = v.u;
    u += 0x7fffu + ((u >> 16) & 1u);
    return (unsigned short)(u >> 16);
}

// ---------------- W transpose: [1024][64] x3 fp32 -> Wt[192][1024] bf16 ----------------
__global__ __launch_bounds__(256) void wtrans_kernel(
    const float* __restrict__ wq, const float* __restrict__ wk,
    const float* __restrict__ wv, unsigned short* __restrict__ Wt)
{
    const int idx = blockIdx.x * 256 + threadIdx.x;   // 192*1024 total
    const int k = idx & 1023;
    const int n = idx >> 10;                          // 0..191
    const float* w = (n < 64) ? wq : ((n < 128) ? wk : wv);
    Wt[(size_t)n * 1024 + k] = f2bf(w[(size_t)k * 64 + (n & 63)]);
}

// ---------------- QKV projection GEMM: M=16384, N=192, K=1024 (bf16 MFMA) -------------
// Writes Q row-major [B*T][64] bf16; K packed Kpk[b][t/16][d/8][t%16][8];
// V packed Vpk[b][t/8][d][t%8]  (both in exact MFMA B-fragment order for attn).
__global__ __launch_bounds__(256) void qkv_proj_kernel(
    const float* __restrict__ x, const unsigned short* __restrict__ Wt,
    unsigned short* __restrict__ Qb, unsigned short* __restrict__ Kpk,
    unsigned short* __restrict__ Vpk)
{
    __shared__ unsigned short Alds[64][40];    // 64 rows x 32 k, +8 pad
    __shared__ unsigned short Wlds[192][40];   // 192 n   x 32 k, +8 pad
    const int tid  = threadIdx.x;
    const int wave = tid >> 6, lane = tid & 63;
    const int g = lane >> 4, lr = lane & 15;
    const int m0 = blockIdx.x * 64;

    f32x4 acc[12];
#pragma unroll
    for (int i = 0; i < 12; ++i) acc[i] = (f32x4)(0.0f);

    for (int k0 = 0; k0 < HID; k0 += 32) {
        __syncthreads();
        { // stage x tile 64x32 fp32 -> bf16 (coalesced float4 loads)
            const int r = tid >> 3;
            const int c = (tid & 7) * 4;
#pragma unroll
            for (int h = 0; h < 2; ++h) {
                const int row = r + h * 32;
                const float4 v = *(const float4*)(x + (size_t)(m0 + row) * HID + k0 + c);
                ushort4 pk = make_ushort4(f2bf(v.x), f2bf(v.y), f2bf(v.z), f2bf(v.w));
                *(ushort4*)&Alds[row][c] = pk;
            }
        }
        { // stage Wt tile 192x32 bf16
#pragma unroll
            for (int j3 = 0; j3 < 3; ++j3) {
                const int j = tid * 3 + j3;          // 0..767
                const int n = j >> 2, part = (j & 3) * 8;
                const uint4 v = *(const uint4*)(Wt + (size_t)n * 1024 + k0 + part);
                *(uint4*)&Wlds[n][part] = v;
            }
        }
        __syncthreads();
        const bf16x8 af = *(const bf16x8*)&Alds[wave * 16 + lr][g * 8];
#pragma unroll
        for (int nt = 0; nt < 12; ++nt) {
            const bf16x8 bfr = *(const bf16x8*)&Wlds[nt * 16 + lr][g * 8];
            acc[nt] = __builtin_amdgcn_mfma_f32_16x16x32_bf16(af, bfr, acc[nt], 0, 0, 0);
        }
    }

    // epilogue: rows t = m0 + wave*16 + g*4 + r ; cols d = nt*16 + lr
    const int rowbase = m0 + wave * 16 + g * 4;
    const int bb = rowbase >> 12;                   // batch
    const size_t bpk = (size_t)bb * (T_LEN * HD);   // 262144 elems per batch
#pragma unroll
    for (int nt = 0; nt < 4; ++nt)
#pragma unroll
        for (int r = 0; r < 4; ++r)
            Qb[(size_t)(rowbase + r) * HD + nt * 16 + lr] = f2bf(acc[nt][r]);
#pragma unroll
    for (int nt = 0; nt < 4; ++nt)
#pragma unroll
        for (int r = 0; r < 4; ++r) {
            const int tl = (rowbase + r) & 4095;
            const int d  = nt * 16 + lr;
            Kpk[bpk + ((((tl >> 4) * 8 + (d >> 3)) * 16 + (tl & 15)) << 3) + (d & 7)]
                = f2bf(acc[nt + 4][r]);
        }
#pragma unroll
    for (int nt = 0; nt < 4; ++nt)
#pragma unroll
        for (int r = 0; r < 4; ++r) {
            const int tl = (rowbase + r) & 4095;
            const int d  = nt * 16 + lr;
            Vpk[bpk + (((tl >> 3) * 64 + d) << 3) + (tl & 7)] = f2bf(acc[nt + 8][r]);
        }
}

// ---------------- Flash attention partials (split-KV, causal, D=64) ----------------
// PAIR stage: 128 kv columns per softmax/LDS round-trip (no masking: full tiles only)
__device__ __forceinline__ void kv_pair(
    const int t0, const int lane, const int g, const int lr,
    const unsigned short* __restrict__ kpk_b, const unsigned short* __restrict__ vpk_b,
    unsigned short (*P)[136],
    const bf16x8 qf0, const bf16x8 qf1,
    f32x4 oacc[4], float mrow[4], float lrow[4])
{
    const float SCL = 0.18033688011112042f;  // (1/8) * log2(e)
    f32x4 s[8];
#pragma unroll
    for (int nt = 0; nt < 8; ++nt) {
        const unsigned short* kp = kpk_b + (((size_t)((t0 >> 4) + nt)) << 10) + (lane << 3);
        const bf16x8 kf0 = *(const bf16x8*)kp;
        const bf16x8 kf1 = *(const bf16x8*)(kp + 512);
        f32x4 a = (f32x4)(0.0f);
        a = __builtin_amdgcn_mfma_f32_16x16x32_bf16(qf0, kf0, a, 0, 0, 0);
        a = __builtin_amdgcn_mfma_f32_16x16x32_bf16(qf1, kf1, a, 0, 0, 0);
        s[nt] = a;
    }
    // row max over 128 cols
    float tm[4];
#pragma unroll
    for (int r = 0; r < 4; ++r) {
        float a = fmaxf(fmaxf(s[0][r], s[1][r]), fmaxf(s[2][r], s[3][r]));
        float b = fmaxf(fmaxf(s[4][r], s[5][r]), fmaxf(s[6][r], s[7][r]));
        tm[r] = fmaxf(a, b);
    }
#pragma unroll
    for (int m = 1; m < 16; m <<= 1)
#pragma unroll
        for (int r = 0; r < 4; ++r)
            tm[r] = fmaxf(tm[r], __shfl_xor(tm[r], m, 64));

    float al[4];
#pragma unroll
    for (int r = 0; r < 4; ++r) {
        const float mn = fmaxf(mrow[r], tm[r]);
        al[r] = __builtin_amdgcn_exp2f((mrow[r] - mn) * SCL);
        mrow[r] = mn;
    }
    float ps[4] = {0.f, 0.f, 0.f, 0.f};
#pragma unroll
    for (int nt = 0; nt < 8; ++nt)
#pragma unroll
        for (int r = 0; r < 4; ++r) {
            const float p = __builtin_amdgcn_exp2f((s[nt][r] - mrow[r]) * SCL);
            ps[r] += p;
            P[g * 4 + r][nt * 16 + lr] = f2bf(p);
        }
#pragma unroll
    for (int r = 0; r < 4; ++r) lrow[r] = lrow[r] * al[r] + ps[r];
#pragma unroll
    for (int dt = 0; dt < 4; ++dt)
#pragma unroll
        for (int r = 0; r < 4; ++r) oacc[dt][r] *= al[r];

    const bf16x8 pf0 = *(const bf16x8*)&P[lr][g * 8];
    const bf16x8 pf1 = *(const bf16x8*)&P[lr][32 + g * 8];
    const bf16x8 pf2 = *(const bf16x8*)&P[lr][64 + g * 8];
    const bf16x8 pf3 = *(const bf16x8*)&P[lr][96 + g * 8];
    const unsigned short* vb = vpk_b + (((size_t)((t0 >> 3) + g)) << 9) + (lr << 3);
#pragma unroll
    for (int dt = 0; dt < 4; ++dt) {
        const bf16x8 vf0 = *(const bf16x8*)(vb + dt * 128);
        const bf16x8 vf1 = *(const bf16x8*)(vb + (4 << 9) + dt * 128);
        const bf16x8 vf2 = *(const bf16x8*)(vb + (8 << 9) + dt * 128);
        const bf16x8 vf3 = *(const bf16x8*)(vb + (12 << 9) + dt * 128);
        oacc[dt] = __builtin_amdgcn_mfma_f32_16x16x32_bf16(pf0, vf0, oacc[dt], 0, 0, 0);
        oacc[dt] = __builtin_amdgcn_mfma_f32_16x16x32_bf16(pf1, vf1, oacc[dt], 0, 0, 0);
        oacc[dt] = __builtin_amdgcn_mfma_f32_16x16x32_bf16(pf2, vf2, oacc[dt], 0, 0, 0);
        oacc[dt] = __builtin_amdgcn_mfma_f32_16x16x32_bf16(pf3, vf3, oacc[dt], 0, 0, 0);
    }
}

// SINGLE 64-kv tile (remainder / masked diagonal)
template <bool MASKED>
__device__ __forceinline__ void kv_single(
    const int t0, const int qw0, const int lane, const int g, const int lr,
    const unsigned short* __restrict__ kpk_b, const unsigned short* __restrict__ vpk_b,
    unsigned short (*P)[136],
    const bf16x8 qf0, const bf16x8 qf1,
    f32x4 oacc[4], float mrow[4], float lrow[4])
{
    const float SCL = 0.18033688011112042f;
    f32x4 s[4];
#pragma unroll
    for (int nt = 0; nt < 4; ++nt) {
        const unsigned short* kp = kpk_b + (((size_t)((t0 >> 4) + nt)) << 10) + (lane << 3);
        const bf16x8 kf0 = *(const bf16x8*)kp;
        const bf16x8 kf1 = *(const bf16x8*)(kp + 512);
        f32x4 a = (f32x4)(0.0f);
        a = __builtin_amdgcn_mfma_f32_16x16x32_bf16(qf0, kf0, a, 0, 0, 0);
        a = __builtin_amdgcn_mfma_f32_16x16x32_bf16(qf1, kf1, a, 0, 0, 0);
        s[nt] = a;
    }
    if (MASKED) {
#pragma unroll
        for (int nt = 0; nt < 4; ++nt) {
            const int kj = t0 + nt * 16 + lr;
#pragma unroll
            for (int r = 0; r < 4; ++r)
                if (kj > qw0 + g * 4 + r) s[nt][r] = -3.0e38f;
        }
    }
    float tm[4];
#pragma unroll
    for (int r = 0; r < 4; ++r)
        tm[r] = fmaxf(fmaxf(s[0][r], s[1][r]), fmaxf(s[2][r], s[3][r]));
#pragma unroll
    for (int m = 1; m < 16; m <<= 1)
#pragma unroll
        for (int r = 0; r < 4; ++r)
            tm[r] = fmaxf(tm[r], __shfl_xor(tm[r], m, 64));

    float al[4];
#pragma unroll
    for (int r = 0; r < 4; ++r) {
        const float mn = fmaxf(mrow[r], tm[r]);
        al[r] = __builtin_amdgcn_exp2f((mrow[r] - mn) * SCL);
        mrow[r] = mn;
    }
    float ps[4] = {0.f, 0.f, 0.f, 0.f};
#pragma unroll
    for (int nt = 0; nt < 4; ++nt)
#pragma unroll
        for (int r = 0; r < 4; ++r) {
            const float p = __builtin_amdgcn_exp2f((s[nt][r] - mrow[r]) * SCL);
            ps[r] += p;
            P[g * 4 + r][nt * 16 + lr] = f2bf(p);
        }
#pragma unroll
    for (int r = 0; r < 4; ++r) lrow[r] = lrow[r] * al[r] + ps[r];
#pragma unroll
    for (int dt = 0; dt < 4; ++dt)
#pragma unroll
        for (int r = 0; r < 4; ++r) oacc[dt][r] *= al[r];

    const bf16x8 pf0 = *(const bf16x8*)&P[lr][g * 8];
    const bf16x8 pf1 = *(const bf16x8*)&P[lr][32 + g * 8];
    const unsigned short* vb = vpk_b + (((size_t)((t0 >> 3) + g)) << 9) + (lr << 3);
#pragma unroll
    for (int dt = 0; dt < 4; ++dt) {
        const bf16x8 vf0 = *(const bf16x8*)(vb + dt * 128);
        const bf16x8 vf1 = *(const bf16x8*)(vb + (4 << 9) + dt * 128);
        oacc[dt] = __builtin_amdgcn_mfma_f32_16x16x32_bf16(pf0, vf0, oacc[dt], 0, 0, 0);
        oacc[dt] = __builtin_amdgcn_mfma_f32_16x16x32_bf16(pf1, vf1, oacc[dt], 0, 0, 0);
    }
}

// grid: ((b*64 + qi)*8 + c); chunk c covers kv [c*512, (c+1)*512)
__global__ __launch_bounds__(256, 4) void attn_part_kernel(
    const unsigned short* __restrict__ Qb, const unsigned short* __restrict__ Kpk,
    const unsigned short* __restrict__ Vpk,
    float* __restrict__ Opart, float* __restrict__ Mpart, float* __restrict__ Lpart)
{
    const int c  = blockIdx.x & 7;
    const int qi = (blockIdx.x >> 3) & 63;
    const int b  = blockIdx.x >> 9;
    const int diagc = qi >> 3;
    if (c > diagc) return;                       // invalid (future) chunk

    __shared__ unsigned short Plds[4][16][136];
    const int tid = threadIdx.x;
    const int wave = tid >> 6, lane = tid & 63;
    const int g = lane >> 4, lr = lane & 15;
    const int qw0 = qi * 64 + wave * 16;         // wave's first q row (in batch)
    const int kvbase = c << 9;
    unsigned short (*P)[136] = Plds[wave];

    const unsigned short* qp = Qb + (size_t)(b * T_LEN + qw0 + lr) * HD + g * 8;
    const bf16x8 qf0 = *(const bf16x8*)qp;
    const bf16x8 qf1 = *(const bf16x8*)(qp + 32);
    const unsigned short* kpk_b = Kpk + (size_t)b * (T_LEN * HD);
    const unsigned short* vpk_b = Vpk + (size_t)b * (T_LEN * HD);

    f32x4 oacc[4];
#pragma unroll
    for (int i = 0; i < 4; ++i) oacc[i] = (f32x4)(0.0f);
    float mrow[4] = {-3.0e38f, -3.0e38f, -3.0e38f, -3.0e38f};
    float lrow[4] = {0.f, 0.f, 0.f, 0.f};

    const bool diag = (c == diagc);
    const int nfull = diag ? ((qw0 + 1 - kvbase) >> 6) : 8;
    int it = 0;
    for (; it + 2 <= nfull; it += 2)
        kv_pair(kvbase + it * 64, lane, g, lr, kpk_b, vpk_b, P, qf0, qf1, oacc, mrow, lrow);
    if (it < nfull)
        kv_single<false>(kvbase + it * 64, qw0, lane, g, lr, kpk_b, vpk_b, P,
                         qf0, qf1, oacc, mrow, lrow);
    if (diag)
        kv_single<true>(kvbase + nfull * 64, qw0, lane, g, lr, kpk_b, vpk_b, P,
                        qf0, qf1, oacc, mrow, lrow);

    // finish the row-sum across the 16-lane group
#pragma unroll
    for (int m = 1; m < 16; m <<= 1)
#pragma unroll
        for (int r = 0; r < 4; ++r) lrow[r] += __shfl_xor(lrow[r], m, 64);

    // write partials (unnormalized)
    float* Op = Opart + ((size_t)blockIdx.x << 12);          // [64][64]
    float* Mp = Mpart + ((size_t)blockIdx.x << 6);
    float* Lp = Lpart + ((size_t)blockIdx.x << 6);
#pragma unroll
    for (int r = 0; r < 4; ++r) {
        const int wrow = wave * 16 + g * 4 + r;
        if (lr == 0) { Mp[wrow] = mrow[r]; Lp[wrow] = lrow[r]; }
#pragma unroll
        for (int dt = 0; dt < 4; ++dt)
            Op[wrow * 64 + dt * 16 + lr] = oacc[dt][r];
    }
}

// ---------------- merge partials: one block per (b, qi) ----------------
__global__ __launch_bounds__(256) void attn_merge_kernel(
    const float* __restrict__ Opart, const float* __restrict__ Mpart,
    const float* __restrict__ Lpart, float* __restrict__ out)
{
    const int qi = blockIdx.x & 63, b = blockIdx.x >> 6;
    const int nch = (qi >> 3) + 1;
    const int t = threadIdx.x;
    const int row = t >> 2, d0 = (t & 3) << 4;
    const size_t pb = (size_t)blockIdx.x << 3;
    const float SCL = 0.18033688011112042f;

    float mv[8], wv[8];
    float M = -3.0e38f;
#pragma unroll
    for (int c = 0; c < 8; ++c) {
        mv[c] = (c < nch) ? Mpart[((pb + c) << 6) + row] : -3.0e38f;
        M = fmaxf(M, mv[c]);
    }
    float L = 0.f;
#pragma unroll
    for (int c = 0; c < 8; ++c) {
        wv[c] = (c < nch) ? __builtin_amdgcn_exp2f((mv[c] - M) * SCL) : 0.f;
        if (c < nch) L += Lpart[((pb + c) << 6) + row] * wv[c];
    }
    const float inv = 1.0f / L;

    f32x4 o[4];
#pragma unroll
    for (int i = 0; i < 4; ++i) o[i] = (f32x4)(0.0f);
#pragma unroll
    for (int c = 0; c < 8; ++c) {
        if (c < nch) {
            const f32x4* src = (const f32x4*)(Opart + (((pb + c) << 6) + row) * 64 + d0);
#pragma unroll
            for (int i = 0; i < 4; ++i) {
                const f32x4 v = src[i];
#pragma unroll
                for (int j = 0; j < 4; ++j) o[i][j] += v[j] * wv[c];
            }
        }
    }
    f32x4* dst = (f32x4*)(out + ((size_t)(b * T_LEN + qi * 64 + row) * HD) + d0);
#pragma unroll
    for (int i = 0; i < 4; ++i) {
        f32x4 v;
#pragma unroll
        for (int j = 0; j < 4; ++j) v[j] = o[i][j] * inv;
        dst[i] = v;
    }
}

extern "C" void kernel_launch(void* const* d_in, const int* in_sizes, int n_in,
                              void* d_out, int out_size, void* d_ws, size_t ws_size,
                              hipStream_t stream) {
    const float* x  = (const float*)d_in[0];
    const float* wq = (const float*)d_in[1];
    const float* wk = (const float*)d_in[2];
    const float* wv = (const float*)d_in[3];
    float* out = (float*)d_out;

    // workspace layout (f32 arrays first for alignment)
    float* Opart = (float*)d_ws;                              // 2048*64*64 f32 = 32 MB
    float* Mpart = Opart + ((size_t)2048 * 4096);             // 2048*64 f32
    float* Lpart = Mpart + ((size_t)2048 * 64);               // 2048*64 f32
    unsigned short* Qb  = (unsigned short*)(Lpart + (size_t)2048 * 64);  // [16384][64] bf16
    unsigned short* Kpk = Qb  + (size_t)NB * T_LEN * HD;      // packed K fragments
    unsigned short* Vpk = Kpk + (size_t)NB * T_LEN * HD;      // packed V fragments
    unsigned short* Wt  = Vpk + (size_t)NB * T_LEN * HD;      // [192][1024]

    wtrans_kernel<<<768, 256, 0, stream>>>(wq, wk, wv, Wt);
    qkv_proj_kernel<<<256, 256, 0, stream>>>(x, Wt, Qb, Kpk, Vpk);
    attn_part_kernel<<<NB * 64 * 8, 256, 0, stream>>>(Qb, Kpk, Vpk, Opart, Mpart, Lpart);
    attn_merge_kernel<<<NB * 64, 256, 0, stream>>>(Opart, Mpart, Lpart, out);
}

// Round 7
// 94.695 us; speedup vs baseline: 2.6027x; 1.0445x over previous
//
#include <hip/hip_runtime.h>

typedef short bf16x8 __attribute__((ext_vector_type(8)));
typedef float f32x4 __attribute__((ext_vector_type(4)));

#define T_LEN 4096
#define NB    4
#define HID   1024
#define HD    64

// fp32 -> bf16 bits, round-to-nearest-even
__device__ __forceinline__ unsigned short f2bf(float f) {
    union { float f; unsigned int u; } v; v.f = f;
    unsigned int u = v.u;
    u += 0x7fffu + ((u >> 16) & 1u);
    return (unsigned short)(u >> 16);
}

// ---- W transpose -> packed MFMA B-fragments Wpk[ks][nt][lane][8] (bf16) ----
// element (n = nt*16 + (lane&15), k = ks*32 + (lane>>4)*8 + j)
__global__ __launch_bounds__(256) void wtrans_kernel(
    const float* __restrict__ wq, const float* __restrict__ wk,
    const float* __restrict__ wv, unsigned short* __restrict__ Wpk)
{
    const int idx = blockIdx.x * 256 + threadIdx.x;   // 192*1024 total
    const int k = idx & 1023;
    const int n = idx >> 10;                          // 0..191
    const float* w = (n < 64) ? wq : ((n < 128) ? wk : wv);
    const int ks = k >> 5, g = (k >> 3) & 3, j = k & 7;
    const int nt = n >> 4, lr = n & 15;
    const int lane = g * 16 + lr;
    Wpk[((size_t)(ks * 12 + nt) << 9) + (lane << 3) + j] =
        f2bf(w[(size_t)k * 64 + (n & 63)]);
}

// ---------------- QKV projection: barrier-free main loop, K-split x4 ----------------
// grid 1024 x 256; block owns 16 rows; wave kq computes K-quarter; LDS combine.
// Writes Q row-major [B*T][64] bf16; K packed Kpk[b][t/16][d/8][t%16][8];
// V packed Vpk[b][t/8][d][t%8].
__global__ __launch_bounds__(256, 4) void qkv_proj_kernel(
    const float* __restrict__ x, const unsigned short* __restrict__ Wpk,
    unsigned short* __restrict__ Qb, unsigned short* __restrict__ Kpk,
    unsigned short* __restrict__ Vpk)
{
    __shared__ float red[3][16][193];   // stride 193: breaks 4-way bank aliasing
    const int tid = threadIdx.x;
    const int kq = tid >> 6, lane = tid & 63;
    const int g = lane >> 4, lr = lane & 15;
    const int t0 = blockIdx.x * 16;

    f32x4 acc[12];
#pragma unroll
    for (int i = 0; i < 12; ++i) acc[i] = (f32x4)(0.0f);

    const float* xrow = x + (size_t)(t0 + lr) * HID;
#pragma unroll 4
    for (int s = 0; s < 8; ++s) {
        const int ks = kq * 8 + s;
        const float4 a0 = *(const float4*)(xrow + ks * 32 + g * 8);
        const float4 a1 = *(const float4*)(xrow + ks * 32 + g * 8 + 4);
        bf16x8 af;
        af[0] = (short)f2bf(a0.x); af[1] = (short)f2bf(a0.y);
        af[2] = (short)f2bf(a0.z); af[3] = (short)f2bf(a0.w);
        af[4] = (short)f2bf(a1.x); af[5] = (short)f2bf(a1.y);
        af[6] = (short)f2bf(a1.z); af[7] = (short)f2bf(a1.w);
        const unsigned short* wp = Wpk + (((size_t)ks * 12) << 9) + (lane << 3);
#pragma unroll
        for (int nt = 0; nt < 12; ++nt) {
            const bf16x8 bfr = *(const bf16x8*)(wp + ((size_t)nt << 9));
            acc[nt] = __builtin_amdgcn_mfma_f32_16x16x32_bf16(af, bfr, acc[nt], 0, 0, 0);
        }
    }

    // combine K-quarters
    if (kq != 0) {
#pragma unroll
        for (int nt = 0; nt < 12; ++nt)
#pragma unroll
            for (int r = 0; r < 4; ++r)
                red[kq - 1][g * 4 + r][nt * 16 + lr] = acc[nt][r];
    }
    __syncthreads();
    if (kq == 0) {
#pragma unroll
        for (int nt = 0; nt < 12; ++nt)
#pragma unroll
            for (int r = 0; r < 4; ++r)
                acc[nt][r] += red[0][g * 4 + r][nt * 16 + lr]
                            + red[1][g * 4 + r][nt * 16 + lr]
                            + red[2][g * 4 + r][nt * 16 + lr];

        // epilogue: rows t0 + g*4 + r ; cols nt*16 + lr
        const int rowb = t0 + g * 4;
        const int bb = t0 >> 12;
        const size_t bpk = (size_t)bb * (T_LEN * HD);
#pragma unroll
        for (int nt = 0; nt < 4; ++nt)
#pragma unroll
            for (int r = 0; r < 4; ++r)
                Qb[(size_t)(rowb + r) * HD + nt * 16 + lr] = f2bf(acc[nt][r]);
#pragma unroll
        for (int nt = 0; nt < 4; ++nt)
#pragma unroll
            for (int r = 0; r < 4; ++r) {
                const int tl = (rowb + r) & 4095;
                const int d  = nt * 16 + lr;
                Kpk[bpk + ((((tl >> 4) * 8 + (d >> 3)) * 16 + (tl & 15)) << 3) + (d & 7)]
                    = f2bf(acc[nt + 4][r]);
            }
#pragma unroll
        for (int nt = 0; nt < 4; ++nt)
#pragma unroll
            for (int r = 0; r < 4; ++r) {
                const int tl = (rowb + r) & 4095;
                const int d  = nt * 16 + lr;
                Vpk[bpk + (((tl >> 3) * 64 + d) << 3) + (tl & 7)] = f2bf(acc[nt + 8][r]);
            }
    }
}

// ---------------- Flash attention partials (split-KV, causal, D=64) ----------------
// PAIR stage: 128 kv columns per softmax/LDS round-trip (no masking: full tiles only)
__device__ __forceinline__ void kv_pair(
    const int t0, const int lane, const int g, const int lr,
    const unsigned short* __restrict__ kpk_b, const unsigned short* __restrict__ vpk_b,
    unsigned short (*P)[136],
    const bf16x8 qf0, const bf16x8 qf1,
    f32x4 oacc[4], float mrow[4], float lrow[4])
{
    const float SCL = 0.18033688011112042f;  // (1/8) * log2(e)
    f32x4 s[8];
#pragma unroll
    for (int nt = 0; nt < 8; ++nt) {
        const unsigned short* kp = kpk_b + (((size_t)((t0 >> 4) + nt)) << 10) + (lane << 3);
        const bf16x8 kf0 = *(const bf16x8*)kp;
        const bf16x8 kf1 = *(const bf16x8*)(kp + 512);
        f32x4 a = (f32x4)(0.0f);
        a = __builtin_amdgcn_mfma_f32_16x16x32_bf16(qf0, kf0, a, 0, 0, 0);
        a = __builtin_amdgcn_mfma_f32_16x16x32_bf16(qf1, kf1, a, 0, 0, 0);
        s[nt] = a;
    }
    // row max over 128 cols
    float tm[4];
#pragma unroll
    for (int r = 0; r < 4; ++r) {
        float a = fmaxf(fmaxf(s[0][r], s[1][r]), fmaxf(s[2][r], s[3][r]));
        float b = fmaxf(fmaxf(s[4][r], s[5][r]), fmaxf(s[6][r], s[7][r]));
        tm[r] = fmaxf(a, b);
    }
#pragma unroll
    for (int m = 1; m < 16; m <<= 1)
#pragma unroll
        for (int r = 0; r < 4; ++r)
            tm[r] = fmaxf(tm[r], __shfl_xor(tm[r], m, 64));

    float al[4];
#pragma unroll
    for (int r = 0; r < 4; ++r) {
        const float mn = fmaxf(mrow[r], tm[r]);
        al[r] = __builtin_amdgcn_exp2f((mrow[r] - mn) * SCL);
        mrow[r] = mn;
    }
    float ps[4] = {0.f, 0.f, 0.f, 0.f};
#pragma unroll
    for (int nt = 0; nt < 8; ++nt)
#pragma unroll
        for (int r = 0; r < 4; ++r) {
            const float p = __builtin_amdgcn_exp2f((s[nt][r] - mrow[r]) * SCL);
            ps[r] += p;
            P[g * 4 + r][nt * 16 + lr] = f2bf(p);
        }
#pragma unroll
    for (int r = 0; r < 4; ++r) lrow[r] = lrow[r] * al[r] + ps[r];
#pragma unroll
    for (int dt = 0; dt < 4; ++dt)
#pragma unroll
        for (int r = 0; r < 4; ++r) oacc[dt][r] *= al[r];

    const bf16x8 pf0 = *(const bf16x8*)&P[lr][g * 8];
    const bf16x8 pf1 = *(const bf16x8*)&P[lr][32 + g * 8];
    const bf16x8 pf2 = *(const bf16x8*)&P[lr][64 + g * 8];
    const bf16x8 pf3 = *(const bf16x8*)&P[lr][96 + g * 8];
    const unsigned short* vb = vpk_b + (((size_t)((t0 >> 3) + g)) << 9) + (lr << 3);
#pragma unroll
    for (int dt = 0; dt < 4; ++dt) {
        const bf16x8 vf0 = *(const bf16x8*)(vb + dt * 128);
        const bf16x8 vf1 = *(const bf16x8*)(vb + (4 << 9) + dt * 128);
        const bf16x8 vf2 = *(const bf16x8*)(vb + (8 << 9) + dt * 128);
        const bf16x8 vf3 = *(const bf16x8*)(vb + (12 << 9) + dt * 128);
        oacc[dt] = __builtin_amdgcn_mfma_f32_16x16x32_bf16(pf0, vf0, oacc[dt], 0, 0, 0);
        oacc[dt] = __builtin_amdgcn_mfma_f32_16x16x32_bf16(pf1, vf1, oacc[dt], 0, 0, 0);
        oacc[dt] = __builtin_amdgcn_mfma_f32_16x16x32_bf16(pf2, vf2, oacc[dt], 0, 0, 0);
        oacc[dt] = __builtin_amdgcn_mfma_f32_16x16x32_bf16(pf3, vf3, oacc[dt], 0, 0, 0);
    }
}

// SINGLE 64-kv tile (remainder / masked diagonal)
template <bool MASKED>
__device__ __forceinline__ void kv_single(
    const int t0, const int qw0, const int lane, const int g, const int lr,
    const unsigned short* __restrict__ kpk_b, const unsigned short* __restrict__ vpk_b,
    unsigned short (*P)[136],
    const bf16x8 qf0, const bf16x8 qf1,
    f32x4 oacc[4], float mrow[4], float lrow[4])
{
    const float SCL = 0.18033688011112042f;
    f32x4 s[4];
#pragma unroll
    for (int nt = 0; nt < 4; ++nt) {
        const unsigned short* kp = kpk_b + (((size_t)((t0 >> 4) + nt)) << 10) + (lane << 3);
        const bf16x8 kf0 = *(const bf16x8*)kp;
        const bf16x8 kf1 = *(const bf16x8*)(kp + 512);
        f32x4 a = (f32x4)(0.0f);
        a = __builtin_amdgcn_mfma_f32_16x16x32_bf16(qf0, kf0, a, 0, 0, 0);
        a = __builtin_amdgcn_mfma_f32_16x16x32_bf16(qf1, kf1, a, 0, 0, 0);
        s[nt] = a;
    }
    if (MASKED) {
#pragma unroll
        for (int nt = 0; nt < 4; ++nt) {
            const int kj = t0 + nt * 16 + lr;
#pragma unroll
            for (int r = 0; r < 4; ++r)
                if (kj > qw0 + g * 4 + r) s[nt][r] = -3.0e38f;
        }
    }
    float tm[4];
#pragma unroll
    for (int r = 0; r < 4; ++r)
        tm[r] = fmaxf(fmaxf(s[0][r], s[1][r]), fmaxf(s[2][r], s[3][r]));
#pragma unroll
    for (int m = 1; m < 16; m <<= 1)
#pragma unroll
        for (int r = 0; r < 4; ++r)
            tm[r] = fmaxf(tm[r], __shfl_xor(tm[r], m, 64));

    float al[4];
#pragma unroll
    for (int r = 0; r < 4; ++r) {
        const float mn = fmaxf(mrow[r], tm[r]);
        al[r] = __builtin_amdgcn_exp2f((mrow[r] - mn) * SCL);
        mrow[r] = mn;
    }
    float ps[4] = {0.f, 0.f, 0.f, 0.f};
#pragma unroll
    for (int nt = 0; nt < 4; ++nt)
#pragma unroll
        for (int r = 0; r < 4; ++r) {
            const float p = __builtin_amdgcn_exp2f((s[nt][r] - mrow[r]) * SCL);
            ps[r] += p;
            P[g * 4 + r][nt * 16 + lr] = f2bf(p);
        }
#pragma unroll
    for (int r = 0; r < 4; ++r) lrow[r] = lrow[r] * al[r] + ps[r];
#pragma unroll
    for (int dt = 0; dt < 4; ++dt)
#pragma unroll
        for (int r = 0; r < 4; ++r) oacc[dt][r] *= al[r];

    const bf16x8 pf0 = *(const bf16x8*)&P[lr][g * 8];
    const bf16x8 pf1 = *(const bf16x8*)&P[lr][32 + g * 8];
    const unsigned short* vb = vpk_b + (((size_t)((t0 >> 3) + g)) << 9) + (lr << 3);
#pragma unroll
    for (int dt = 0; dt < 4; ++dt) {
        const bf16x8 vf0 = *(const bf16x8*)(vb + dt * 128);
        const bf16x8 vf1 = *(const bf16x8*)(vb + (4 << 9) + dt * 128);
        oacc[dt] = __builtin_amdgcn_mfma_f32_16x16x32_bf16(pf0, vf0, oacc[dt], 0, 0, 0);
        oacc[dt] = __builtin_amdgcn_mfma_f32_16x16x32_bf16(pf1, vf1, oacc[dt], 0, 0, 0);
    }
}

// grid: ((b*64 + qi)*8 + c); chunk c covers kv [c*512, (c+1)*512)
__global__ __launch_bounds__(256, 4) void attn_part_kernel(
    const unsigned short* __restrict__ Qb, const unsigned short* __restrict__ Kpk,
    const unsigned short* __restrict__ Vpk,
    float* __restrict__ Opart, float* __restrict__ Mpart, float* __restrict__ Lpart)
{
    const int c  = blockIdx.x & 7;
    const int qi = (blockIdx.x >> 3) & 63;
    const int b  = blockIdx.x >> 9;
    const int diagc = qi >> 3;
    if (c > diagc) return;                       // invalid (future) chunk

    __shared__ unsigned short Plds[4][16][136];
    const int tid = threadIdx.x;
    const int wave = tid >> 6, lane = tid & 63;
    const int g = lane >> 4, lr = lane & 15;
    const int qw0 = qi * 64 + wave * 16;         // wave's first q row (in batch)
    const int kvbase = c << 9;
    unsigned short (*P)[136] = Plds[wave];

    const unsigned short* qp = Qb + (size_t)(b * T_LEN + qw0 + lr) * HD + g * 8;
    const bf16x8 qf0 = *(const bf16x8*)qp;
    const bf16x8 qf1 = *(const bf16x8*)(qp + 32);
    const unsigned short* kpk_b = Kpk + (size_t)b * (T_LEN * HD);
    const unsigned short* vpk_b = Vpk + (size_t)b * (T_LEN * HD);

    f32x4 oacc[4];
#pragma unroll
    for (int i = 0; i < 4; ++i) oacc[i] = (f32x4)(0.0f);
    float mrow[4] = {-3.0e38f, -3.0e38f, -3.0e38f, -3.0e38f};
    float lrow[4] = {0.f, 0.f, 0.f, 0.f};

    const bool diag = (c == diagc);
    const int nfull = diag ? ((qw0 + 1 - kvbase) >> 6) : 8;
    int it = 0;
    for (; it + 2 <= nfull; it += 2)
        kv_pair(kvbase + it * 64, lane, g, lr, kpk_b, vpk_b, P, qf0, qf1, oacc, mrow, lrow);
    if (it < nfull)
        kv_single<false>(kvbase + it * 64, qw0, lane, g, lr, kpk_b, vpk_b, P,
                         qf0, qf1, oacc, mrow, lrow);
    if (diag)
        kv_single<true>(kvbase + nfull * 64, qw0, lane, g, lr, kpk_b, vpk_b, P,
                        qf0, qf1, oacc, mrow, lrow);

    // finish the row-sum across the 16-lane group
#pragma unroll
    for (int m = 1; m < 16; m <<= 1)
#pragma unroll
        for (int r = 0; r < 4; ++r) lrow[r] += __shfl_xor(lrow[r], m, 64);

    // write partials (unnormalized)
    float* Op = Opart + ((size_t)blockIdx.x << 12);          // [64][64]
    float* Mp = Mpart + ((size_t)blockIdx.x << 6);
    float* Lp = Lpart + ((size_t)blockIdx.x << 6);
#pragma unroll
    for (int r = 0; r < 4; ++r) {
        const int wrow = wave * 16 + g * 4 + r;
        if (lr == 0) { Mp[wrow] = mrow[r]; Lp[wrow] = lrow[r]; }
#pragma unroll
        for (int dt = 0; dt < 4; ++dt)
            Op[wrow * 64 + dt * 16 + lr] = oacc[dt][r];
    }
}

// ---------------- merge partials: one block per (b, qi) ----------------
__global__ __launch_bounds__(256) void attn_merge_kernel(
    const float* __restrict__ Opart, const float* __restrict__ Mpart,
    const float* __restrict__ Lpart, float* __restrict__ out)
{
    const int qi = blockIdx.x & 63, b = blockIdx.x >> 6;
    const int nch = (qi >> 3) + 1;
    const int t = threadIdx.x;
    const int row = t >> 2, d0 = (t & 3) << 4;
    const size_t pb = (size_t)blockIdx.x << 3;
    const float SCL = 0.18033688011112042f;

    float mv[8], wv[8];
    float M = -3.0e38f;
#pragma unroll
    for (int c = 0; c < 8; ++c) {
        mv[c] = (c < nch) ? Mpart[((pb + c) << 6) + row] : -3.0e38f;
        M = fmaxf(M, mv[c]);
    }
    float L = 0.f;
#pragma unroll
    for (int c = 0; c < 8; ++c) {
        wv[c] = (c < nch) ? __builtin_amdgcn_exp2f((mv[c] - M) * SCL) : 0.f;
        if (c < nch) L += Lpart[((pb + c) << 6) + row] * wv[c];
    }
    const float inv = 1.0f / L;

    f32x4 o[4];
#pragma unroll
    for (int i = 0; i < 4; ++i) o[i] = (f32x4)(0.0f);
#pragma unroll
    for (int c = 0; c < 8; ++c) {
        if (c < nch) {
            const f32x4* src = (const f32x4*)(Opart + (((pb + c) << 6) + row) * 64 + d0);
#pragma unroll
            for (int i = 0; i < 4; ++i) {
                const f32x4 v = src[i];
#pragma unroll
                for (int j = 0; j < 4; ++j) o[i][j] += v[j] * wv[c];
            }
        }
    }
    f32x4* dst = (f32x4*)(out + ((size_t)(b * T_LEN + qi * 64 + row) * HD) + d0);
#pragma unroll
    for (int i = 0; i < 4; ++i) {
        f32x4 v;
#pragma unroll
        for (int j = 0; j < 4; ++j) v[j] = o[i][j] * inv;
        dst[i] = v;
    }
}

extern "C" void kernel_launch(void* const* d_in, const int* in_sizes, int n_in,
                              void* d_out, int out_size, void* d_ws, size_t ws_size,
                              hipStream_t stream) {
    const float* x  = (const float*)d_in[0];
    const float* wq = (const float*)d_in[1];
    const float* wk = (const float*)d_in[2];
    const float* wv = (const float*)d_in[3];
    float* out = (float*)d_out;

    // workspace layout (f32 arrays first for alignment)
    float* Opart = (float*)d_ws;                              // 2048*64*64 f32 = 32 MB
    float* Mpart = Opart + ((size_t)2048 * 4096);             // 2048*64 f32
    float* Lpart = Mpart + ((size_t)2048 * 64);               // 2048*64 f32
    unsigned short* Qb  = (unsigned short*)(Lpart + (size_t)2048 * 64);  // [16384][64] bf16
    unsigned short* Kpk = Qb  + (size_t)NB * T_LEN * HD;      // packed K fragments
    unsigned short* Vpk = Kpk + (size_t)NB * T_LEN * HD;      // packed V fragments
    unsigned short* Wpk = Vpk + (size_t)NB * T_LEN * HD;      // packed W fragments [32*12*512]

    wtrans_kernel<<<768, 256, 0, stream>>>(wq, wk, wv, Wpk);
    qkv_proj_kernel<<<1024, 256, 0, stream>>>(x, Wpk, Qb, Kpk, Vpk);
    attn_part_kernel<<<NB * 64 * 8, 256, 0, stream>>>(Qb, Kpk, Vpk, Opart, Mpart, Lpart);
    attn_merge_kernel<<<NB * 64, 256, 0, stream>>>(Opart, Mpart, Lpart, out);
}

// Round 8
// 92.607 us; speedup vs baseline: 2.6614x; 1.0225x over previous
//
#include <hip/hip_runtime.h>

typedef short bf16x8 __attribute__((ext_vector_type(8)));
typedef float f32x4 __attribute__((ext_vector_type(4)));

#define T_LEN 4096
#define NB    4
#define HID   1024
#define HD    64

// fp32 -> bf16 bits, round-to-nearest-even
__device__ __forceinline__ unsigned short f2bf(float f) {
    union { float f; unsigned int u; } v; v.f = f;
    unsigned int u = v.u;
    u += 0x7fffu + ((u >> 16) & 1u);
    return (unsigned short)(u >> 16);
}

// ---- W transpose -> packed MFMA B-fragments Wpk[ks][nt][lane][8] (bf16) ----
__global__ __launch_bounds__(256) void wtrans_kernel(
    const float* __restrict__ wq, const float* __restrict__ wk,
    const float* __restrict__ wv, unsigned short* __restrict__ Wpk)
{
    const int idx = blockIdx.x * 256 + threadIdx.x;   // 192*1024 total
    const int k = idx & 1023;
    const int n = idx >> 10;                          // 0..191
    const float* w = (n < 64) ? wq : ((n < 128) ? wk : wv);
    const int ks = k >> 5, g = (k >> 3) & 3, j = k & 7;
    const int nt = n >> 4, lr = n & 15;
    const int lane = g * 16 + lr;
    Wpk[((size_t)(ks * 12 + nt) << 9) + (lane << 3) + j] =
        f2bf(w[(size_t)k * 64 + (n & 63)]);
}

// ---------------- QKV projection: barrier-free main loop, K-split x4 ----------------
__global__ __launch_bounds__(256, 4) void qkv_proj_kernel(
    const float* __restrict__ x, const unsigned short* __restrict__ Wpk,
    unsigned short* __restrict__ Qb, unsigned short* __restrict__ Kpk,
    unsigned short* __restrict__ Vpk)
{
    __shared__ float red[3][16][193];
    const int tid = threadIdx.x;
    const int kq = tid >> 6, lane = tid & 63;
    const int g = lane >> 4, lr = lane & 15;
    const int t0 = blockIdx.x * 16;

    f32x4 acc[12];
#pragma unroll
    for (int i = 0; i < 12; ++i) acc[i] = (f32x4)(0.0f);

    const float* xrow = x + (size_t)(t0 + lr) * HID;
#pragma unroll 4
    for (int s = 0; s < 8; ++s) {
        const int ks = kq * 8 + s;
        const float4 a0 = *(const float4*)(xrow + ks * 32 + g * 8);
        const float4 a1 = *(const float4*)(xrow + ks * 32 + g * 8 + 4);
        bf16x8 af;
        af[0] = (short)f2bf(a0.x); af[1] = (short)f2bf(a0.y);
        af[2] = (short)f2bf(a0.z); af[3] = (short)f2bf(a0.w);
        af[4] = (short)f2bf(a1.x); af[5] = (short)f2bf(a1.y);
        af[6] = (short)f2bf(a1.z); af[7] = (short)f2bf(a1.w);
        const unsigned short* wp = Wpk + (((size_t)ks * 12) << 9) + (lane << 3);
#pragma unroll
        for (int nt = 0; nt < 12; ++nt) {
            const bf16x8 bfr = *(const bf16x8*)(wp + ((size_t)nt << 9));
            acc[nt] = __builtin_amdgcn_mfma_f32_16x16x32_bf16(af, bfr, acc[nt], 0, 0, 0);
        }
    }

    if (kq != 0) {
#pragma unroll
        for (int nt = 0; nt < 12; ++nt)
#pragma unroll
            for (int r = 0; r < 4; ++r)
                red[kq - 1][g * 4 + r][nt * 16 + lr] = acc[nt][r];
    }
    __syncthreads();
    if (kq == 0) {
#pragma unroll
        for (int nt = 0; nt < 12; ++nt)
#pragma unroll
            for (int r = 0; r < 4; ++r)
                acc[nt][r] += red[0][g * 4 + r][nt * 16 + lr]
                            + red[1][g * 4 + r][nt * 16 + lr]
                            + red[2][g * 4 + r][nt * 16 + lr];

        const int rowb = t0 + g * 4;
        const int bb = t0 >> 12;
        const size_t bpk = (size_t)bb * (T_LEN * HD);
#pragma unroll
        for (int nt = 0; nt < 4; ++nt)
#pragma unroll
            for (int r = 0; r < 4; ++r)
                Qb[(size_t)(rowb + r) * HD + nt * 16 + lr] = f2bf(acc[nt][r]);
#pragma unroll
        for (int nt = 0; nt < 4; ++nt)
#pragma unroll
            for (int r = 0; r < 4; ++r) {
                const int tl = (rowb + r) & 4095;
                const int d  = nt * 16 + lr;
                Kpk[bpk + ((((tl >> 4) * 8 + (d >> 3)) * 16 + (tl & 15)) << 3) + (d & 7)]
                    = f2bf(acc[nt + 4][r]);
            }
#pragma unroll
        for (int nt = 0; nt < 4; ++nt)
#pragma unroll
            for (int r = 0; r < 4; ++r) {
                const int tl = (rowb + r) & 4095;
                const int d  = nt * 16 + lr;
                Vpk[bpk + (((tl >> 3) * 64 + d) << 3) + (tl & 7)] = f2bf(acc[nt + 8][r]);
            }
    }
}

// ---------------- Flash attention partials (split-KV, causal, D=64) ----------------
// PAIR stage: 128 kv columns; phased for MLP: [all K loads] -> QK -> [all V loads]
// -> softmax -> P round-trip -> PV.
__device__ __forceinline__ void kv_pair(
    const int t0, const int lane, const int g, const int lr,
    const unsigned short* __restrict__ kpk_b, const unsigned short* __restrict__ vpk_b,
    unsigned short (*P)[136],
    const bf16x8 qf0, const bf16x8 qf1,
    f32x4 oacc[4], float mrow[4], float lrow[4])
{
    const float SCL = 0.18033688011112042f;  // (1/8) * log2(e)

    // Phase 1: all 16 K-fragment loads issued together
    bf16x8 kf[16];
    const unsigned short* kbase = kpk_b + (((size_t)(t0 >> 4)) << 10) + (lane << 3);
#pragma unroll
    for (int nt = 0; nt < 8; ++nt) {
        kf[2 * nt]     = *(const bf16x8*)(kbase + ((size_t)nt << 10));
        kf[2 * nt + 1] = *(const bf16x8*)(kbase + ((size_t)nt << 10) + 512);
    }
    // Phase 2: QK^T MFMAs
    f32x4 s[8];
#pragma unroll
    for (int nt = 0; nt < 8; ++nt) {
        f32x4 a = (f32x4)(0.0f);
        a = __builtin_amdgcn_mfma_f32_16x16x32_bf16(qf0, kf[2 * nt], a, 0, 0, 0);
        a = __builtin_amdgcn_mfma_f32_16x16x32_bf16(qf1, kf[2 * nt + 1], a, 0, 0, 0);
        s[nt] = a;
    }
    // Phase 3a: all 16 V-fragment loads issued now; latency hides under softmax VALU
    bf16x8 vf[16];
    const unsigned short* vb = vpk_b + (((size_t)((t0 >> 3) + g)) << 9) + (lr << 3);
#pragma unroll
    for (int dt = 0; dt < 4; ++dt) {
        vf[4 * dt]     = *(const bf16x8*)(vb + dt * 128);
        vf[4 * dt + 1] = *(const bf16x8*)(vb + (4 << 9) + dt * 128);
        vf[4 * dt + 2] = *(const bf16x8*)(vb + (8 << 9) + dt * 128);
        vf[4 * dt + 3] = *(const bf16x8*)(vb + (12 << 9) + dt * 128);
    }
    // Phase 3b: softmax (row max over 128 cols, rescale, exp, P->LDS)
    float tm[4];
#pragma unroll
    for (int r = 0; r < 4; ++r) {
        float a = fmaxf(fmaxf(s[0][r], s[1][r]), fmaxf(s[2][r], s[3][r]));
        float b = fmaxf(fmaxf(s[4][r], s[5][r]), fmaxf(s[6][r], s[7][r]));
        tm[r] = fmaxf(a, b);
    }
#pragma unroll
    for (int m = 1; m < 16; m <<= 1)
#pragma unroll
        for (int r = 0; r < 4; ++r)
            tm[r] = fmaxf(tm[r], __shfl_xor(tm[r], m, 64));

    float al[4];
#pragma unroll
    for (int r = 0; r < 4; ++r) {
        const float mn = fmaxf(mrow[r], tm[r]);
        al[r] = __builtin_amdgcn_exp2f((mrow[r] - mn) * SCL);
        mrow[r] = mn;
    }
    float ps[4] = {0.f, 0.f, 0.f, 0.f};
#pragma unroll
    for (int nt = 0; nt < 8; ++nt)
#pragma unroll
        for (int r = 0; r < 4; ++r) {
            const float p = __builtin_amdgcn_exp2f((s[nt][r] - mrow[r]) * SCL);
            ps[r] += p;
            P[g * 4 + r][nt * 16 + lr] = f2bf(p);
        }
#pragma unroll
    for (int r = 0; r < 4; ++r) lrow[r] = lrow[r] * al[r] + ps[r];
#pragma unroll
    for (int dt = 0; dt < 4; ++dt)
#pragma unroll
        for (int r = 0; r < 4; ++r) oacc[dt][r] *= al[r];

    // Phase 4: P fragments from LDS + PV MFMAs (V already in registers)
    const bf16x8 pf0 = *(const bf16x8*)&P[lr][g * 8];
    const bf16x8 pf1 = *(const bf16x8*)&P[lr][32 + g * 8];
    const bf16x8 pf2 = *(const bf16x8*)&P[lr][64 + g * 8];
    const bf16x8 pf3 = *(const bf16x8*)&P[lr][96 + g * 8];
#pragma unroll
    for (int dt = 0; dt < 4; ++dt) {
        oacc[dt] = __builtin_amdgcn_mfma_f32_16x16x32_bf16(pf0, vf[4 * dt],     oacc[dt], 0, 0, 0);
        oacc[dt] = __builtin_amdgcn_mfma_f32_16x16x32_bf16(pf1, vf[4 * dt + 1], oacc[dt], 0, 0, 0);
        oacc[dt] = __builtin_amdgcn_mfma_f32_16x16x32_bf16(pf2, vf[4 * dt + 2], oacc[dt], 0, 0, 0);
        oacc[dt] = __builtin_amdgcn_mfma_f32_16x16x32_bf16(pf3, vf[4 * dt + 3], oacc[dt], 0, 0, 0);
    }
}

// SINGLE 64-kv tile (remainder / masked diagonal), same phasing
template <bool MASKED>
__device__ __forceinline__ void kv_single(
    const int t0, const int qw0, const int lane, const int g, const int lr,
    const unsigned short* __restrict__ kpk_b, const unsigned short* __restrict__ vpk_b,
    unsigned short (*P)[136],
    const bf16x8 qf0, const bf16x8 qf1,
    f32x4 oacc[4], float mrow[4], float lrow[4])
{
    const float SCL = 0.18033688011112042f;
    bf16x8 kf[8];
    const unsigned short* kbase = kpk_b + (((size_t)(t0 >> 4)) << 10) + (lane << 3);
#pragma unroll
    for (int nt = 0; nt < 4; ++nt) {
        kf[2 * nt]     = *(const bf16x8*)(kbase + ((size_t)nt << 10));
        kf[2 * nt + 1] = *(const bf16x8*)(kbase + ((size_t)nt << 10) + 512);
    }
    f32x4 s[4];
#pragma unroll
    for (int nt = 0; nt < 4; ++nt) {
        f32x4 a = (f32x4)(0.0f);
        a = __builtin_amdgcn_mfma_f32_16x16x32_bf16(qf0, kf[2 * nt], a, 0, 0, 0);
        a = __builtin_amdgcn_mfma_f32_16x16x32_bf16(qf1, kf[2 * nt + 1], a, 0, 0, 0);
        s[nt] = a;
    }
    bf16x8 vf[8];
    const unsigned short* vb = vpk_b + (((size_t)((t0 >> 3) + g)) << 9) + (lr << 3);
#pragma unroll
    for (int dt = 0; dt < 4; ++dt) {
        vf[2 * dt]     = *(const bf16x8*)(vb + dt * 128);
        vf[2 * dt + 1] = *(const bf16x8*)(vb + (4 << 9) + dt * 128);
    }
    if (MASKED) {
#pragma unroll
        for (int nt = 0; nt < 4; ++nt) {
            const int kj = t0 + nt * 16 + lr;
#pragma unroll
            for (int r = 0; r < 4; ++r)
                if (kj > qw0 + g * 4 + r) s[nt][r] = -3.0e38f;
        }
    }
    float tm[4];
#pragma unroll
    for (int r = 0; r < 4; ++r)
        tm[r] = fmaxf(fmaxf(s[0][r], s[1][r]), fmaxf(s[2][r], s[3][r]));
#pragma unroll
    for (int m = 1; m < 16; m <<= 1)
#pragma unroll
        for (int r = 0; r < 4; ++r)
            tm[r] = fmaxf(tm[r], __shfl_xor(tm[r], m, 64));

    float al[4];
#pragma unroll
    for (int r = 0; r < 4; ++r) {
        const float mn = fmaxf(mrow[r], tm[r]);
        al[r] = __builtin_amdgcn_exp2f((mrow[r] - mn) * SCL);
        mrow[r] = mn;
    }
    float ps[4] = {0.f, 0.f, 0.f, 0.f};
#pragma unroll
    for (int nt = 0; nt < 4; ++nt)
#pragma unroll
        for (int r = 0; r < 4; ++r) {
            const float p = __builtin_amdgcn_exp2f((s[nt][r] - mrow[r]) * SCL);
            ps[r] += p;
            P[g * 4 + r][nt * 16 + lr] = f2bf(p);
        }
#pragma unroll
    for (int r = 0; r < 4; ++r) lrow[r] = lrow[r] * al[r] + ps[r];
#pragma unroll
    for (int dt = 0; dt < 4; ++dt)
#pragma unroll
        for (int r = 0; r < 4; ++r) oacc[dt][r] *= al[r];

    const bf16x8 pf0 = *(const bf16x8*)&P[lr][g * 8];
    const bf16x8 pf1 = *(const bf16x8*)&P[lr][32 + g * 8];
#pragma unroll
    for (int dt = 0; dt < 4; ++dt) {
        oacc[dt] = __builtin_amdgcn_mfma_f32_16x16x32_bf16(pf0, vf[2 * dt],     oacc[dt], 0, 0, 0);
        oacc[dt] = __builtin_amdgcn_mfma_f32_16x16x32_bf16(pf1, vf[2 * dt + 1], oacc[dt], 0, 0, 0);
    }
}

// grid: ((b*64 + qi)*8 + c); chunk c covers kv [c*512, (c+1)*512)
__global__ __launch_bounds__(256, 3) void attn_part_kernel(
    const unsigned short* __restrict__ Qb, const unsigned short* __restrict__ Kpk,
    const unsigned short* __restrict__ Vpk,
    float* __restrict__ Opart, float* __restrict__ Mpart, float* __restrict__ Lpart)
{
    const int c  = blockIdx.x & 7;
    const int qi = (blockIdx.x >> 3) & 63;
    const int b  = blockIdx.x >> 9;
    const int diagc = qi >> 3;
    if (c > diagc) return;                       // invalid (future) chunk

    __shared__ unsigned short Plds[4][16][136];
    const int tid = threadIdx.x;
    const int wave = tid >> 6, lane = tid & 63;
    const int g = lane >> 4, lr = lane & 15;
    const int qw0 = qi * 64 + wave * 16;
    const int kvbase = c << 9;
    unsigned short (*P)[136] = Plds[wave];

    const unsigned short* qp = Qb + (size_t)(b * T_LEN + qw0 + lr) * HD + g * 8;
    const bf16x8 qf0 = *(const bf16x8*)qp;
    const bf16x8 qf1 = *(const bf16x8*)(qp + 32);
    const unsigned short* kpk_b = Kpk + (size_t)b * (T_LEN * HD);
    const unsigned short* vpk_b = Vpk + (size_t)b * (T_LEN * HD);

    f32x4 oacc[4];
#pragma unroll
    for (int i = 0; i < 4; ++i) oacc[i] = (f32x4)(0.0f);
    float mrow[4] = {-3.0e38f, -3.0e38f, -3.0e38f, -3.0e38f};
    float lrow[4] = {0.f, 0.f, 0.f, 0.f};

    const bool diag = (c == diagc);
    const int nfull = diag ? ((qw0 + 1 - kvbase) >> 6) : 8;
    int it = 0;
    for (; it + 2 <= nfull; it += 2)
        kv_pair(kvbase + it * 64, lane, g, lr, kpk_b, vpk_b, P, qf0, qf1, oacc, mrow, lrow);
    if (it < nfull)
        kv_single<false>(kvbase + it * 64, qw0, lane, g, lr, kpk_b, vpk_b, P,
                         qf0, qf1, oacc, mrow, lrow);
    if (diag)
        kv_single<true>(kvbase + nfull * 64, qw0, lane, g, lr, kpk_b, vpk_b, P,
                        qf0, qf1, oacc, mrow, lrow);

#pragma unroll
    for (int m = 1; m < 16; m <<= 1)
#pragma unroll
        for (int r = 0; r < 4; ++r) lrow[r] += __shfl_xor(lrow[r], m, 64);

    float* Op = Opart + ((size_t)blockIdx.x << 12);
    float* Mp = Mpart + ((size_t)blockIdx.x << 6);
    float* Lp = Lpart + ((size_t)blockIdx.x << 6);
#pragma unroll
    for (int r = 0; r < 4; ++r) {
        const int wrow = wave * 16 + g * 4 + r;
        if (lr == 0) { Mp[wrow] = mrow[r]; Lp[wrow] = lrow[r]; }
#pragma unroll
        for (int dt = 0; dt < 4; ++dt)
            Op[wrow * 64 + dt * 16 + lr] = oacc[dt][r];
    }
}

// ---------------- merge partials: one block per (b, qi) ----------------
__global__ __launch_bounds__(256) void attn_merge_kernel(
    const float* __restrict__ Opart, const float* __restrict__ Mpart,
    const float* __restrict__ Lpart, float* __restrict__ out)
{
    const int qi = blockIdx.x & 63, b = blockIdx.x >> 6;
    const int nch = (qi >> 3) + 1;
    const int t = threadIdx.x;
    const int row = t >> 2, d0 = (t & 3) << 4;
    const size_t pb = (size_t)blockIdx.x << 3;
    const float SCL = 0.18033688011112042f;

    float mv[8], wv[8];
    float M = -3.0e38f;
#pragma unroll
    for (int c = 0; c < 8; ++c) {
        mv[c] = (c < nch) ? Mpart[((pb + c) << 6) + row] : -3.0e38f;
        M = fmaxf(M, mv[c]);
    }
    float L = 0.f;
#pragma unroll
    for (int c = 0; c < 8; ++c) {
        wv[c] = (c < nch) ? __builtin_amdgcn_exp2f((mv[c] - M) * SCL) : 0.f;
        if (c < nch) L += Lpart[((pb + c) << 6) + row] * wv[c];
    }
    const float inv = 1.0f / L;

    f32x4 o[4];
#pragma unroll
    for (int i = 0; i < 4; ++i) o[i] = (f32x4)(0.0f);
#pragma unroll
    for (int c = 0; c < 8; ++c) {
        if (c < nch) {
            const f32x4* src = (const f32x4*)(Opart + (((pb + c) << 6) + row) * 64 + d0);
#pragma unroll
            for (int i = 0; i < 4; ++i) {
                const f32x4 v = src[i];
#pragma unroll
                for (int j = 0; j < 4; ++j) o[i][j] += v[j] * wv[c];
            }
        }
    }
    f32x4* dst = (f32x4*)(out + ((size_t)(b * T_LEN + qi * 64 + row) * HD) + d0);
#pragma unroll
    for (int i = 0; i < 4; ++i) {
        f32x4 v;
#pragma unroll
        for (int j = 0; j < 4; ++j) v[j] = o[i][j] * inv;
        dst[i] = v;
    }
}

extern "C" void kernel_launch(void* const* d_in, const int* in_sizes, int n_in,
                              void* d_out, int out_size, void* d_ws, size_t ws_size,
                              hipStream_t stream) {
    const float* x  = (const float*)d_in[0];
    const float* wq = (const float*)d_in[1];
    const float* wk = (const float*)d_in[2];
    const float* wv = (const float*)d_in[3];
    float* out = (float*)d_out;

    float* Opart = (float*)d_ws;                              // 2048*64*64 f32 = 32 MB
    float* Mpart = Opart + ((size_t)2048 * 4096);
    float* Lpart = Mpart + ((size_t)2048 * 64);
    unsigned short* Qb  = (unsigned short*)(Lpart + (size_t)2048 * 64);
    unsigned short* Kpk = Qb  + (size_t)NB * T_LEN * HD;
    unsigned short* Vpk = Kpk + (size_t)NB * T_LEN * HD;
    unsigned short* Wpk = Vpk + (size_t)NB * T_LEN * HD;

    wtrans_kernel<<<768, 256, 0, stream>>>(wq, wk, wv, Wpk);
    qkv_proj_kernel<<<1024, 256, 0, stream>>>(x, Wpk, Qb, Kpk, Vpk);
    attn_part_kernel<<<NB * 64 * 8, 256, 0, stream>>>(Qb, Kpk, Vpk, Opart, Mpart, Lpart);
    attn_merge_kernel<<<NB * 64, 256, 0, stream>>>(Opart, Mpart, Lpart, out);
}